// Round 5
// baseline (1182.174 us; speedup 1.0000x reference)
//
#include <hip/hip_runtime.h>

#define NP    128
#define NITER 100
#define BLK   256
#define RSC   72.13475204444817f    // log2(e)/EPS, EPS=0.02
#define IRSC  0.013862943611198906f // EPS*ln2 = 1/RSC

template<int CTRL>
__device__ __forceinline__ float dppf(float x) {
  return __int_as_float(__builtin_amdgcn_update_dpp(
      0, __float_as_int(x), CTRL, 0xf, 0xf, false));
}
// sum all-reduce across a 16-lane DPP row (rotations 1,2,4,8)
__device__ __forceinline__ float rowsum16(float x) {
  x += dppf<0x121>(x);  // row_ror:1
  x += dppf<0x122>(x);  // row_ror:2
  x += dppf<0x124>(x);  // row_ror:4
  x += dppf<0x128>(x);  // row_ror:8
  return x;
}
__device__ __forceinline__ float wsum64(float x) {
  #pragma unroll
  for (int s = 1; s < 64; s <<= 1) x += __shfl_xor(x, s);
  return x;
}

// Linear-domain Sinkhorn, single register tile:
//   K = 2^(-dist*RSC);  P[n] = a[n]/(K Q)[n];  Q[m] = b[m]/(K^T P)[m]
// Thread (i,j) of 16x16 holds ONLY A = K[8i..8i+7][8j..8j+7] (64 VGPR).
// Row pass: per-lane partials over cols, DPP all-reduce over the 16 j-lanes
//   -> every lane owns full P for its 8 rows (lane-local).
// Col pass: c[kc] = sum_kr A[kr][kc]*p[kr] (no transpose tile needed!),
//   reduce over i = shfl_xor 16/32 in-wave + 4-wave LDS partial combine.
// ~116 VGPR -> launch_bounds(256,4): all-arch registers, 4 blocks/CU,
// 1024 blocks fully resident in ONE round.
__global__ __launch_bounds__(BLK, 4) void emd_sinkhorn(
    const float* __restrict__ j1g, const float* __restrict__ j2g,
    float* __restrict__ out)
{
  __shared__ __align__(16) float x1s[NP], y1s[NP], x2s[NP], y2s[NP];
  __shared__ __align__(16) float ah[NP + 4], bh[NP + 4];
  __shared__ __align__(16) float Qv[NP + 4];
  __shared__ __align__(16) float part[4][NP + 8];   // row stride 544B, 16-aligned
  __shared__ float red[4];

  const int t  = threadIdx.x;
  const int l  = t & 63;
  const int wv = t >> 6;
  const int i  = t >> 4;   // row block 0..15 (rows 8i..8i+7)
  const int j  = t & 15;   // col block 0..15 (cols 8j..8j+7)
  const int b  = blockIdx.x;
  const float* J1 = j1g + (size_t)b * (NP * 3);
  const float* J2 = j2g + (size_t)b * (NP * 3);

  // ---- load particles ----
  if (t < NP) {
    x1s[t] = J1[3*t]; y1s[t] = J1[3*t+1]; ah[t] = J1[3*t+2];
    x2s[t] = J2[3*t]; y2s[t] = J2[3*t+1]; bh[t] = J2[3*t+2];
  }
  __syncthreads();

  // ---- exact energies from raw weights ----
  const float e1 = wsum64(ah[l] + ah[l + 64]);
  const float e2 = wsum64(bh[l] + bh[l + 64]);
  const float dE = fabsf(e2 - e1);
  __syncthreads();  // raw-weight reads done before in-place flooring

  if (t < NP) { ah[t] = fmaxf(ah[t], 1e-30f); bh[t] = fmaxf(bh[t], 1e-30f); }
  if (t == 0) {
    ah[NP] = fmaxf(fmaxf(e2 - e1, 0.0f), 1e-30f);
    bh[NP] = fmaxf(fmaxf(e1 - e2, 0.0f), 1e-30f);
  }
  if (t <= NP) Qv[t] = 1.0f;   // initial scaling vector (g = 0)

  // ---- build register tile A = K[8i..][8j..] (once) ----
  float A[8][8];
  {
    float xc[8], yc[8];
    #pragma unroll
    for (int k = 0; k < 8; ++k) { xc[k] = x2s[8*j + k]; yc[k] = y2s[8*j + k]; }
    #pragma unroll
    for (int kr = 0; kr < 8; ++kr) {
      const float xr = x1s[8*i + kr], yr = y1s[8*i + kr];
      #pragma unroll
      for (int kc = 0; kc < 8; ++kc) {
        const float dx = xc[kc] - xr + 1e-12f, dy = yc[kc] - yr + 1e-12f;
        A[kr][kc] = __builtin_amdgcn_exp2f(-__builtin_sqrtf(dx*dx + dy*dy) * RSC);
      }
    }
  }
  __syncthreads();  // floors + Qv init visible

  const float4 a4a = *(const float4*)&ah[8*i];
  const float4 a4b = *(const float4*)&ah[8*i + 4];
  const float aslk = ah[NP];
  const float bT   = bh[t <= NP ? t : NP];   // combine-phase b (col t)

  float pv[8], p128;

  for (int it = 0; it < NITER; ++it) {
    // ---------- row pass: P[n] = a[n] * rcp( (K Q)[n] ) ----------
    const float4 qa = *(const float4*)&Qv[8*j];
    const float4 qb = *(const float4*)&Qv[8*j + 4];
    const float q128 = Qv[NP];
    float r[8];
    #pragma unroll
    for (int kr = 0; kr < 8; ++kr)
      r[kr] = ((A[kr][0]*qa.x + A[kr][1]*qa.y) + (A[kr][2]*qa.z + A[kr][3]*qa.w))
            + ((A[kr][4]*qb.x + A[kr][5]*qb.y) + (A[kr][6]*qb.z + A[kr][7]*qb.w));
    float rs = ((qa.x + qa.y) + (qa.z + qa.w)) + ((qb.x + qb.y) + (qb.z + qb.w));
    #pragma unroll
    for (int kr = 0; kr < 8; ++kr) r[kr] = rowsum16(r[kr]);
    rs = rowsum16(rs);
    #pragma unroll
    for (int kr = 0; kr < 8; ++kr) pv[kr] = 0.0f;  // overwritten below
    pv[0] = a4a.x * __builtin_amdgcn_rcpf(r[0] + q128);
    pv[1] = a4a.y * __builtin_amdgcn_rcpf(r[1] + q128);
    pv[2] = a4a.z * __builtin_amdgcn_rcpf(r[2] + q128);
    pv[3] = a4a.w * __builtin_amdgcn_rcpf(r[3] + q128);
    pv[4] = a4b.x * __builtin_amdgcn_rcpf(r[4] + q128);
    pv[5] = a4b.y * __builtin_amdgcn_rcpf(r[5] + q128);
    pv[6] = a4b.z * __builtin_amdgcn_rcpf(r[6] + q128);
    pv[7] = a4b.w * __builtin_amdgcn_rcpf(r[7] + q128);
    p128  = aslk  * __builtin_amdgcn_rcpf(rs   + q128);

    // ---------- col pass: partial (K^T P) over this thread's 8 rows ----------
    float c[8];
    #pragma unroll
    for (int kc = 0; kc < 8; ++kc)
      c[kc] = ((A[0][kc]*pv[0] + A[1][kc]*pv[1]) + (A[2][kc]*pv[2] + A[3][kc]*pv[3]))
            + ((A[4][kc]*pv[4] + A[5][kc]*pv[5]) + (A[6][kc]*pv[6] + A[7][kc]*pv[7]));
    float ps = ((pv[0] + pv[1]) + (pv[2] + pv[3])) + ((pv[4] + pv[5]) + (pv[6] + pv[7]));
    // reduce over i within wave (lane bits 4,5 — j bits untouched)
    #pragma unroll
    for (int kc = 0; kc < 8; ++kc) {
      c[kc] += __shfl_xor(c[kc], 16);
      c[kc] += __shfl_xor(c[kc], 32);
    }
    ps += __shfl_xor(ps, 16);
    ps += __shfl_xor(ps, 32);
    if ((t & 48) == 0) {   // one i-copy per wave: lanes 0..15, j spans all cols
      *(float4*)&part[wv][8*j]     = make_float4(c[0], c[1], c[2], c[3]);
      *(float4*)&part[wv][8*j + 4] = make_float4(c[4], c[5], c[6], c[7]);
    }
    if ((t & 63) == 0) part[wv][NP] = ps;   // wave's 32-row sum of P
    __syncthreads();
    // ---------- combine: Q[m] = b[m] * rcp( sum_w part + P[128] ) ----------
    if (t <= NP) {
      const float s = (part[0][t] + part[1][t]) + (part[2][t] + part[3][t]);
      Qv[t] = bT * __builtin_amdgcn_rcpf(s + p128);  // K[128][m]=1 -> +P[128]
    }
    __syncthreads();
  }

  // ---- emd = sum_{n,m<128} d * P[n]*Q[m]*K[n][m] + dE ;  d = -log2(K)/RSC ----
  float qc[8];
  {
    const float4 q0 = *(const float4*)&Qv[8*j];
    const float4 q1 = *(const float4*)&Qv[8*j + 4];
    qc[0]=q0.x; qc[1]=q0.y; qc[2]=q0.z; qc[3]=q0.w;
    qc[4]=q1.x; qc[5]=q1.y; qc[6]=q1.z; qc[7]=q1.w;
  }
  float acc = 0.0f;
  #pragma unroll
  for (int kr = 0; kr < 8; ++kr) {
    #pragma unroll
    for (int kc = 0; kc < 8; ++kc) {
      const float k = A[kr][kc];
      const float d = -__builtin_amdgcn_logf(k) * IRSC;
      acc = fmaf(d, (pv[kr] * k) * qc[kc], acc);
    }
  }
  acc = wsum64(acc);
  if (l == 0) red[wv] = acc;
  __syncthreads();
  if (t == 0) out[b] = ((red[0] + red[1]) + (red[2] + red[3])) + dE;
}

extern "C" void kernel_launch(void* const* d_in, const int* in_sizes, int n_in,
                              void* d_out, int out_size, void* d_ws, size_t ws_size,
                              hipStream_t stream) {
  const float* j1 = (const float*)d_in[0];
  const float* j2 = (const float*)d_in[1];
  float* outp = (float*)d_out;
  const int batch = in_sizes[0] / (NP * 3);
  hipLaunchKernelGGL(emd_sinkhorn, dim3(batch), dim3(BLK), 0, stream,
                     j1, j2, outp);
}

// Round 6
// 311.270 us; speedup vs baseline: 3.7979x; 3.7979x over previous
//
#include <hip/hip_runtime.h>

#define NP    128
#define NITER 100
#define BLK   512
#define RSC   72.13475204444817f    // log2(e)/EPS, EPS=0.02
#define IRSC  0.013862943611198906f // EPS*ln2 = 1/RSC

template<int CTRL>
__device__ __forceinline__ float dppf(float x) {
  return __int_as_float(__builtin_amdgcn_update_dpp(
      0, __float_as_int(x), CTRL, 0xf, 0xf, false));
}
// sum all-reduce across a 16-lane DPP row (rotations 1,2,4,8)
__device__ __forceinline__ float rowsum16(float x) {
  x += dppf<0x121>(x);  // row_ror:1
  x += dppf<0x122>(x);  // row_ror:2
  x += dppf<0x124>(x);  // row_ror:4
  x += dppf<0x128>(x);  // row_ror:8
  return x;
}
__device__ __forceinline__ float wsum64(float x) {
  #pragma unroll
  for (int s = 1; s < 64; s <<= 1) x += __shfl_xor(x, s);
  return x;
}

// Linear-domain Sinkhorn, small register tile (anti-spill sizing):
//   K = 2^(-dist*RSC);  P[n] = a[n]/(K Q)[n];  Q[m] = b[m]/(K^T P)[m]
// 512 threads: thread (i=t>>4 in 0..31, j=t&15) holds A = K[4i..4i+3][8j..8j+7]
// = 32 VGPRs. Total demand ~80 regs << 128-reg budget of launch_bounds(512,4)
// -> all-arch VGPRs, no AGPR shuffling (R3/R4), no scratch spill (R5).
// Row pass: 32 FMA + DPP rowsum16 over the 16 j-lanes -> P lane-local (4 rows).
// Col pass: 32 FMA + shfl_xor 16/32 over i-blocks + 8-wave LDS combine.
__global__ __launch_bounds__(BLK, 4) void emd_sinkhorn(
    const float* __restrict__ j1g, const float* __restrict__ j2g,
    float* __restrict__ out)
{
  __shared__ __align__(16) float x1s[NP], y1s[NP], x2s[NP], y2s[NP];
  __shared__ __align__(16) float ah[NP + 4], bh[NP + 4];
  __shared__ __align__(16) float Qv[NP + 4];
  __shared__ __align__(16) float part[8][NP + 8];   // row stride 544B (16-aligned)
  __shared__ float red[8];

  const int t  = threadIdx.x;
  const int l  = t & 63;
  const int wv = t >> 6;   // wave 0..7
  const int i  = t >> 4;   // row block 0..31 (rows 4i..4i+3)
  const int j  = t & 15;   // col block 0..15 (cols 8j..8j+7)
  const int b  = blockIdx.x;
  const float* J1 = j1g + (size_t)b * (NP * 3);
  const float* J2 = j2g + (size_t)b * (NP * 3);

  // ---- load particles ----
  if (t < NP) {
    x1s[t] = J1[3*t]; y1s[t] = J1[3*t+1]; ah[t] = J1[3*t+2];
    x2s[t] = J2[3*t]; y2s[t] = J2[3*t+1]; bh[t] = J2[3*t+2];
  }
  __syncthreads();

  // ---- exact energies from raw weights (redundant per wave, deterministic) ----
  const float e1 = wsum64(ah[l] + ah[l + 64]);
  const float e2 = wsum64(bh[l] + bh[l + 64]);
  const float dE = fabsf(e2 - e1);
  __syncthreads();  // raw-weight reads done before in-place flooring

  if (t < NP) { ah[t] = fmaxf(ah[t], 1e-30f); bh[t] = fmaxf(bh[t], 1e-30f); }
  if (t == 0) {
    ah[NP] = fmaxf(fmaxf(e2 - e1, 0.0f), 1e-30f);
    bh[NP] = fmaxf(fmaxf(e1 - e2, 0.0f), 1e-30f);
  }
  if (t <= NP) Qv[t] = 1.0f;   // initial scaling vector (g = 0)

  // ---- build register tile A = K[4i..][8j..] (once) ----
  float A[4][8];
  {
    float xc[8], yc[8];
    #pragma unroll
    for (int k = 0; k < 8; ++k) { xc[k] = x2s[8*j + k]; yc[k] = y2s[8*j + k]; }
    #pragma unroll
    for (int kr = 0; kr < 4; ++kr) {
      const float xr = x1s[4*i + kr], yr = y1s[4*i + kr];
      #pragma unroll
      for (int kc = 0; kc < 8; ++kc) {
        const float dx = xc[kc] - xr + 1e-12f, dy = yc[kc] - yr + 1e-12f;
        A[kr][kc] = __builtin_amdgcn_exp2f(-__builtin_sqrtf(dx*dx + dy*dy) * RSC);
      }
    }
  }
  __syncthreads();  // floors + Qv init visible

  const float4 a4  = *(const float4*)&ah[4*i];
  const float  aslk = ah[NP];
  const float  bT   = bh[t <= NP ? t : NP];   // combine-phase b (col t)

  float pv[4], p128;

  for (int it = 0; it < NITER; ++it) {
    // ---------- row pass: P[n] = a[n] * rcp( (K Q)[n] ) ----------
    const float4 qa = *(const float4*)&Qv[8*j];
    const float4 qb = *(const float4*)&Qv[8*j + 4];
    const float q128 = Qv[NP];
    float r[4];
    #pragma unroll
    for (int kr = 0; kr < 4; ++kr)
      r[kr] = ((A[kr][0]*qa.x + A[kr][1]*qa.y) + (A[kr][2]*qa.z + A[kr][3]*qa.w))
            + ((A[kr][4]*qb.x + A[kr][5]*qb.y) + (A[kr][6]*qb.z + A[kr][7]*qb.w));
    float rs = ((qa.x + qa.y) + (qa.z + qa.w)) + ((qb.x + qb.y) + (qb.z + qb.w));
    #pragma unroll
    for (int kr = 0; kr < 4; ++kr) r[kr] = rowsum16(r[kr]);
    rs = rowsum16(rs);
    pv[0] = a4.x * __builtin_amdgcn_rcpf(r[0] + q128);
    pv[1] = a4.y * __builtin_amdgcn_rcpf(r[1] + q128);
    pv[2] = a4.z * __builtin_amdgcn_rcpf(r[2] + q128);
    pv[3] = a4.w * __builtin_amdgcn_rcpf(r[3] + q128);
    p128  = aslk * __builtin_amdgcn_rcpf(rs   + q128);

    // ---------- col pass: partial (K^T P) over this thread's 4 rows ----------
    float c[8];
    #pragma unroll
    for (int kc = 0; kc < 8; ++kc)
      c[kc] = (A[0][kc]*pv[0] + A[1][kc]*pv[1]) + (A[2][kc]*pv[2] + A[3][kc]*pv[3]);
    float ps = (pv[0] + pv[1]) + (pv[2] + pv[3]);
    // reduce over i within wave (lane bits 4,5 — j bits untouched)
    #pragma unroll
    for (int kc = 0; kc < 8; ++kc) {
      c[kc] += __shfl_xor(c[kc], 16);
      c[kc] += __shfl_xor(c[kc], 32);
    }
    ps += __shfl_xor(ps, 16);
    ps += __shfl_xor(ps, 32);
    if ((t & 48) == 0) {   // lanes 0..15 of each wave: j spans all 16 col blocks
      *(float4*)&part[wv][8*j]     = make_float4(c[0], c[1], c[2], c[3]);
      *(float4*)&part[wv][8*j + 4] = make_float4(c[4], c[5], c[6], c[7]);
    }
    if (l == 0) part[wv][NP] = ps;   // wave's 16-row P-sum
    __syncthreads();
    // ---------- combine: Q[m] = b[m] * rcp( sum_w part + P[128] ) ----------
    if (t <= NP) {
      const float s = ((part[0][t] + part[1][t]) + (part[2][t] + part[3][t]))
                    + ((part[4][t] + part[5][t]) + (part[6][t] + part[7][t]));
      Qv[t] = bT * __builtin_amdgcn_rcpf(s + p128);  // K[128][m]=1 -> +P[128]
    }
    __syncthreads();
  }

  // ---- emd = sum_{n,m<128} d * P[n]*Q[m]*K[n][m] + dE ;  d = -log2(K)/RSC ----
  float qc[8];
  {
    const float4 q0 = *(const float4*)&Qv[8*j];
    const float4 q1 = *(const float4*)&Qv[8*j + 4];
    qc[0]=q0.x; qc[1]=q0.y; qc[2]=q0.z; qc[3]=q0.w;
    qc[4]=q1.x; qc[5]=q1.y; qc[6]=q1.z; qc[7]=q1.w;
  }
  float acc = 0.0f;
  #pragma unroll
  for (int kr = 0; kr < 4; ++kr) {
    #pragma unroll
    for (int kc = 0; kc < 8; ++kc) {
      const float k = A[kr][kc];
      const float d = -__builtin_amdgcn_logf(k) * IRSC;
      acc = fmaf(d, (pv[kr] * k) * qc[kc], acc);
    }
  }
  acc = wsum64(acc);
  if (l == 0) red[wv] = acc;
  __syncthreads();
  if (t == 0)
    out[b] = (((red[0] + red[1]) + (red[2] + red[3]))
            + ((red[4] + red[5]) + (red[6] + red[7]))) + dE;
}

extern "C" void kernel_launch(void* const* d_in, const int* in_sizes, int n_in,
                              void* d_out, int out_size, void* d_ws, size_t ws_size,
                              hipStream_t stream) {
  const float* j1 = (const float*)d_in[0];
  const float* j2 = (const float*)d_in[1];
  float* outp = (float*)d_out;
  const int batch = in_sizes[0] / (NP * 3);
  hipLaunchKernelGGL(emd_sinkhorn, dim3(batch), dim3(BLK), 0, stream,
                     j1, j2, outp);
}

// Round 7
// 192.700 us; speedup vs baseline: 6.1348x; 1.6153x over previous
//
#include <hip/hip_runtime.h>

#define NP    128
#define NITER 100
#define BLK   512
#define RSC   72.13475204444817f    // log2(e)/EPS, EPS=0.02
#define IRSC  0.013862943611198906f // EPS*ln2 = 1/RSC

typedef __attribute__((ext_vector_type(8))) short bf16x8;
typedef __attribute__((ext_vector_type(4))) float f32x4;

template<int CTRL>
__device__ __forceinline__ float dppf(float x) {
  return __int_as_float(__builtin_amdgcn_update_dpp(
      0, __float_as_int(x), CTRL, 0xf, 0xf, false));
}
__device__ __forceinline__ float rowsum16(float x) {
  x += dppf<0x121>(x); x += dppf<0x122>(x);
  x += dppf<0x124>(x); x += dppf<0x128>(x);
  return x;
}
__device__ __forceinline__ float wsum64(float x) {
  #pragma unroll
  for (int s = 1; s < 64; s <<= 1) x += __shfl_xor(x, s);
  return x;
}
__device__ __forceinline__ unsigned short f2bf(float f) {   // RNE
  unsigned u = __float_as_uint(f);
  u += 0x7fffu + ((u >> 16) & 1u);
  return (unsigned short)(u >> 16);
}
__device__ __forceinline__ float bf2f(unsigned short h) {
  return __uint_as_float(((unsigned)h) << 16);
}

// Linear-domain Sinkhorn on the MATRIX pipe.
//   K = 2^(-dist*RSC) in bf16 MFMA fragments (iteration-invariant):
//     wave w: KA = rows 16w..16w+15 of K (A-operand form),
//             KB = cols 16w..16w+15 of K (B-operand form) — both built
//     directly from coordinates, no transpose shuffles.
//   pass1: D = mfma(KA, replicated-Q)  -> P[n] = a[n]*rcp(D[n] + Q128)
//   pass2: D = mfma(replicated-P, KB)  -> Q[m] = b[m]*rcp(D[m] + P128)
//   Slack bin (index 128, K row/col of ones) via per-wave strip sums in LDS.
// Fragment maps (16x16x32 bf16): A: row=l&15, k=(l>>4)*8+i; B: col=l&15,
// same k-map; C/D: col=l&15, row=(l>>4)*4+reg (m89-verified). A/B share the
// k-map, so any k-permutation error cancels in the dot product.
__global__ __launch_bounds__(BLK, 4) void emd_sinkhorn(
    const float* __restrict__ j1g, const float* __restrict__ j2g,
    float* __restrict__ out)
{
  __shared__ __align__(16) float x1s[NP], y1s[NP], x2s[NP], y2s[NP];
  __shared__ __align__(16) float ah[NP + 4], bh[NP + 4];
  __shared__ __align__(16) unsigned short Qlds[NP], Plds[NP];
  __shared__ __align__(16) float sumQ[8], sumP[8];
  __shared__ float red[8];

  const int t  = threadIdx.x;
  const int l  = t & 63;
  const int wv = t >> 6;   // wave 0..7: owns K-rows/cols 16wv..16wv+15
  const int lg = l >> 4;   // k-group 0..3
  const int li = l & 15;   // tile row (pass1) / tile col (pass2)
  const int b  = blockIdx.x;
  const float* J1 = j1g + (size_t)b * (NP * 3);
  const float* J2 = j2g + (size_t)b * (NP * 3);

  // ---- load particles ----
  if (t < NP) {
    x1s[t] = J1[3*t]; y1s[t] = J1[3*t+1]; ah[t] = J1[3*t+2];
    x2s[t] = J2[3*t]; y2s[t] = J2[3*t+1]; bh[t] = J2[3*t+2];
  }
  __syncthreads();

  // ---- exact energies from raw weights (redundant per wave) ----
  const float e1 = wsum64(ah[l] + ah[l + 64]);
  const float e2 = wsum64(bh[l] + bh[l + 64]);
  const float dE = fabsf(e2 - e1);
  __syncthreads();  // raw reads done before in-place flooring

  if (t < NP) { ah[t] = fmaxf(ah[t], 1e-30f); bh[t] = fmaxf(bh[t], 1e-30f); }
  if (t == 0) {
    ah[NP] = fmaxf(fmaxf(e2 - e1, 0.0f), 1e-30f);
    bh[NP] = fmaxf(fmaxf(e1 - e2, 0.0f), 1e-30f);
  }
  if (t < NP) Qlds[t] = 0x3F80;           // bf16 1.0 (g = 0)
  if (l == 0) sumQ[wv] = 16.0f;           // each 16-col strip of ones
  __syncthreads();

  // ---- per-thread coefficients ----
  const float aslk = ah[NP], bslk = bh[NP];
  float a4[4];
  #pragma unroll
  for (int q = 0; q < 4; ++q) a4[q] = ah[16*wv + lg*4 + q];
  const float bcol = bh[16*wv + li];

  // ---- build K fragments once ----
  bf16x8 KA[4], KB[4];
  {
    const int nA = 16*wv + li;           // pass1 A: K row
    const int mB = 16*wv + li;           // pass2 B: K col
    const float x1A = x1s[nA], y1A = y1s[nA];
    const float x2B = x2s[mB], y2B = y2s[mB];
    #pragma unroll
    for (int c = 0; c < 4; ++c) {
      #pragma unroll
      for (int i = 0; i < 8; ++i) {
        const int k = 32*c + lg*8 + i;
        float dx = x2s[k] - x1A + 1e-12f;          // K[nA][k]
        float dy = y2s[k] - y1A + 1e-12f;
        KA[c][i] = (short)f2bf(
            __builtin_amdgcn_exp2f(-__builtin_sqrtf(dx*dx + dy*dy) * RSC));
        dx = x2B - x1s[k] + 1e-12f;                // K[k][mB]
        dy = y2B - y1s[k] + 1e-12f;
        KB[c][i] = (short)f2bf(
            __builtin_amdgcn_exp2f(-__builtin_sqrtf(dx*dx + dy*dy) * RSC));
      }
    }
  }

  float q128 = 1.0f, p128;
  bf16x8 qf[4];

  for (int it = 0; it < NITER; ++it) {
    // ---------- pass1: P = a * rcp(K·Q + Q128) ----------
    #pragma unroll
    for (int c = 0; c < 4; ++c)
      qf[c] = *(const bf16x8*)&Qlds[c*32 + lg*8];   // broadcast reads
    const float4 s0 = *(const float4*)&sumQ[0];
    const float4 s1 = *(const float4*)&sumQ[4];
    const float SQ = ((s0.x + s0.y) + (s0.z + s0.w))
                   + ((s1.x + s1.y) + (s1.z + s1.w));
    f32x4 acc = {0.f, 0.f, 0.f, 0.f};
    #pragma unroll
    for (int c = 0; c < 4; ++c)
      acc = __builtin_amdgcn_mfma_f32_16x16x32_bf16(KA[c], qf[c], acc, 0, 0, 0);
    p128 = aslk * __builtin_amdgcn_rcpf(SQ + q128);
    float pv[4];
    #pragma unroll
    for (int q = 0; q < 4; ++q)
      pv[q] = a4[q] * __builtin_amdgcn_rcpf(acc[q] + q128);
    // strip sum of P (16 rows of this wave)
    float ps = (pv[0] + pv[1]) + (pv[2] + pv[3]);
    ps += __shfl_xor(ps, 16);
    ps += __shfl_xor(ps, 32);
    if (l == 0) sumP[wv] = ps;
    if (li == 0) {                       // write 4 bf16 P values
      uint2 pk;
      pk.x = (unsigned)f2bf(pv[0]) | ((unsigned)f2bf(pv[1]) << 16);
      pk.y = (unsigned)f2bf(pv[2]) | ((unsigned)f2bf(pv[3]) << 16);
      *(uint2*)&Plds[16*wv + lg*4] = pk;
    }
    __syncthreads();

    // ---------- pass2: Q = b * rcp(K^T·P + P128) ----------
    bf16x8 pf[4];
    #pragma unroll
    for (int c = 0; c < 4; ++c)
      pf[c] = *(const bf16x8*)&Plds[c*32 + lg*8];
    const float4 t0 = *(const float4*)&sumP[0];
    const float4 t1 = *(const float4*)&sumP[4];
    const float SP = ((t0.x + t0.y) + (t0.z + t0.w))
                   + ((t1.x + t1.y) + (t1.z + t1.w));
    f32x4 acc2 = {0.f, 0.f, 0.f, 0.f};
    #pragma unroll
    for (int c = 0; c < 4; ++c)
      acc2 = __builtin_amdgcn_mfma_f32_16x16x32_bf16(pf[c], KB[c], acc2, 0, 0, 0);
    q128 = bslk * __builtin_amdgcn_rcpf(SP + p128);
    const float qv = bcol * __builtin_amdgcn_rcpf(acc2[0] + p128);
    const float qs = rowsum16(qv);       // strip sum over the 16 cols
    if (l == 0) sumQ[wv] = qs;
    if (l < 16) Qlds[16*wv + li] = f2bf(qv);
    __syncthreads();
  }

  // ---- emd = sum d * P[n] Q[m] K[n][m] + dE ; d = -log2(K)*EPS*ln2 ----
  const float Pn = bf2f(Plds[16*wv + li]);   // row n = 16wv+li
  #pragma unroll
  for (int c = 0; c < 4; ++c)
    qf[c] = *(const bf16x8*)&Qlds[c*32 + lg*8];
  float acc = 0.0f;
  #pragma unroll
  for (int c = 0; c < 4; ++c) {
    #pragma unroll
    for (int i = 0; i < 8; ++i) {
      const float kk = bf2f((unsigned short)KA[c][i]);
      const float qm = bf2f((unsigned short)qf[c][i]);
      const float d  = -__builtin_amdgcn_logf(kk) * IRSC;
      acc = fmaf(d, (Pn * kk) * qm, acc);
    }
  }
  acc = wsum64(acc);
  if (l == 0) red[wv] = acc;
  __syncthreads();
  if (t == 0)
    out[b] = (((red[0] + red[1]) + (red[2] + red[3]))
            + ((red[4] + red[5]) + (red[6] + red[7]))) + dE;
}

extern "C" void kernel_launch(void* const* d_in, const int* in_sizes, int n_in,
                              void* d_out, int out_size, void* d_ws, size_t ws_size,
                              hipStream_t stream) {
  const float* j1 = (const float*)d_in[0];
  const float* j2 = (const float*)d_in[1];
  float* outp = (float*)d_out;
  const int batch = in_sizes[0] / (NP * 3);
  hipLaunchKernelGGL(emd_sinkhorn, dim3(batch), dim3(BLK), 0, stream,
                     j1, j2, outp);
}